// Round 1
// baseline (10491.850 us; speedup 1.0000x reference)
//
#include <hip/hip_runtime.h>
#include <hip/hip_bf16.h>

// Problem constants (from reference)
#define N_NODES  60000
#define N_EDGES  240000
#define N_REL    4
#define N_GRAPHS 128
#define D_IN     768
#define D_H      256
#define N_LAYERS 6

static inline int cdiv(int a, int b) { return (a + b - 1) / b; }

// ---------------------------------------------------------------------------
// Edge-count kernels: cnt[r*N + dst] = #edges with (rel=r, dst), then invert
// ---------------------------------------------------------------------------
__global__ void count_edges(const int* __restrict__ rel, const int* __restrict__ dst,
                            float* __restrict__ cnt, int E) {
    int e = blockIdx.x * 256 + threadIdx.x;
    if (e < E) atomicAdd(&cnt[rel[e] * N_NODES + dst[e]], 1.0f);
}

__global__ void invert_cnt(float* __restrict__ cnt, int n) {
    int i = blockIdx.x * 256 + threadIdx.x;
    if (i < n) cnt[i] = 1.0f / fmaxf(cnt[i], 1.0f);
}

// ---------------------------------------------------------------------------
// fp32 tiled GEMM: C[M,N] = A[M,K] @ B[K,N] (+ bias). BM=BN=64, BK=16,
// 256 threads, 4x4 per thread.
// ---------------------------------------------------------------------------
#define BM 64
#define BN 64
#define BK 16

__global__ __launch_bounds__(256) void gemm_f32(
    const float* __restrict__ A, const float* __restrict__ B,
    const float* __restrict__ bias, float* __restrict__ C,
    int M, int N, int K)
{
    __shared__ float As[BK][BM + 4];  // padded, row stride 68 floats (16B-aligned)
    __shared__ float Bs[BK][BN];

    const int bm = blockIdx.x * BM;
    const int bn = blockIdx.y * BN;
    const int tid = threadIdx.x;

    const int tr = tid >> 4;   // 0..15
    const int tc = tid & 15;   // 0..15

    // A-tile load mapping: 64 rows x 16 cols, one float4 per thread
    const int a_row = tid >> 2;         // 0..63
    const int a_col = (tid & 3) * 4;    // 0,4,8,12
    // B-tile load mapping: 16 rows x 64 cols, one float4 per thread
    const int b_row = tid >> 4;         // 0..15
    const int b_col = (tid & 15) * 4;   // 0..60

    float acc[4][4] = {};

    for (int k0 = 0; k0 < K; k0 += BK) {
        float4 av = make_float4(0.f, 0.f, 0.f, 0.f);
        int gr = bm + a_row;
        if (gr < M) av = *reinterpret_cast<const float4*>(&A[(long)gr * K + k0 + a_col]);
        As[a_col + 0][a_row] = av.x;
        As[a_col + 1][a_row] = av.y;
        As[a_col + 2][a_row] = av.z;
        As[a_col + 3][a_row] = av.w;

        float4 bv = *reinterpret_cast<const float4*>(&B[(long)(k0 + b_row) * N + bn + b_col]);
        *reinterpret_cast<float4*>(&Bs[b_row][b_col]) = bv;

        __syncthreads();

        #pragma unroll
        for (int k = 0; k < BK; ++k) {
            float4 a = *reinterpret_cast<const float4*>(&As[k][tr * 4]);
            float4 b = *reinterpret_cast<const float4*>(&Bs[k][tc * 4]);
            acc[0][0] += a.x * b.x; acc[0][1] += a.x * b.y; acc[0][2] += a.x * b.z; acc[0][3] += a.x * b.w;
            acc[1][0] += a.y * b.x; acc[1][1] += a.y * b.y; acc[1][2] += a.y * b.z; acc[1][3] += a.y * b.w;
            acc[2][0] += a.z * b.x; acc[2][1] += a.z * b.y; acc[2][2] += a.z * b.z; acc[2][3] += a.z * b.w;
            acc[3][0] += a.w * b.x; acc[3][1] += a.w * b.y; acc[3][2] += a.w * b.z; acc[3][3] += a.w * b.w;
        }
        __syncthreads();
    }

    float4 bv = make_float4(0.f, 0.f, 0.f, 0.f);
    if (bias) bv = *reinterpret_cast<const float4*>(&bias[bn + tc * 4]);

    #pragma unroll
    for (int i = 0; i < 4; ++i) {
        int row = bm + tr * 4 + i;
        if (row < M) {
            float4 o;
            o.x = acc[i][0] + bv.x;
            o.y = acc[i][1] + bv.y;
            o.z = acc[i][2] + bv.z;
            o.w = acc[i][3] + bv.w;
            *reinterpret_cast<float4*>(&C[(long)row * N + bn + tc * 4]) = o;
        }
    }
}

// ---------------------------------------------------------------------------
// Scatter: for each edge of relation r, out[dst] += h_r[src] * inv_cnt[r,dst]
// One wave (64 lanes) per edge, 4 floats per lane (256 channels).
// ---------------------------------------------------------------------------
__global__ __launch_bounds__(256) void scatter_mean_add(
    const float* __restrict__ h_r,
    const int* __restrict__ src, const int* __restrict__ dst,
    const int* __restrict__ rel, const float* __restrict__ inv_cnt,
    float* __restrict__ out, int E, int r)
{
    int e = blockIdx.x * 4 + (threadIdx.x >> 6);
    if (e >= E) return;
    if (rel[e] != r) return;
    int lane = threadIdx.x & 63;
    int s = src[e], d = dst[e];
    float scale = inv_cnt[r * N_NODES + d];
    float4 v = *reinterpret_cast<const float4*>(&h_r[(long)s * D_H + lane * 4]);
    float* o = &out[(long)d * D_H + lane * 4];
    atomicAdd(o + 0, v.x * scale);
    atomicAdd(o + 1, v.y * scale);
    atomicAdd(o + 2, v.z * scale);
    atomicAdd(o + 3, v.w * scale);
}

// ---------------------------------------------------------------------------
// In-place ReLU, float4 vectorized
// ---------------------------------------------------------------------------
__global__ void relu_kernel(float* __restrict__ x, long n4) {
    long i = (long)blockIdx.x * 256 + threadIdx.x;
    if (i < n4) {
        float4 v = reinterpret_cast<float4*>(x)[i];
        v.x = fmaxf(v.x, 0.f); v.y = fmaxf(v.y, 0.f);
        v.z = fmaxf(v.z, 0.f); v.w = fmaxf(v.w, 0.f);
        reinterpret_cast<float4*>(x)[i] = v;
    }
}

// ---------------------------------------------------------------------------
// Pooling: one block per graph; batch is sorted so the graph's nodes are a
// contiguous range found by binary search. Thread t handles channel t.
// Writes g_feat[g*512 + 0..255] = mean, [256..511] = max.
// ---------------------------------------------------------------------------
__global__ __launch_bounds__(256) void pool_kernel(
    const float* __restrict__ h, const int* __restrict__ batch,
    float* __restrict__ g_feat)
{
    int g = blockIdx.x;
    int t = threadIdx.x;
    __shared__ int s_lo, s_hi;
    if (t == 0) {
        int lo = 0, hi = N_NODES;
        while (lo < hi) { int m = (lo + hi) >> 1; if (batch[m] < g) lo = m + 1; else hi = m; }
        s_lo = lo;
        int lo2 = lo, hi2 = N_NODES;
        while (lo2 < hi2) { int m = (lo2 + hi2) >> 1; if (batch[m] < g + 1) lo2 = m + 1; else hi2 = m; }
        s_hi = lo2;
    }
    __syncthreads();
    int lo = s_lo, hi = s_hi;
    float sum = 0.f, mx = 0.f;  // h is post-ReLU (>=0) so max init 0 is safe
    for (int n = lo; n < hi; ++n) {
        float v = h[(long)n * D_H + t];
        sum += v;
        mx = fmaxf(mx, v);
    }
    float cnt = (float)(hi - lo);
    g_feat[g * 512 + t]       = sum / fmaxf(cnt, 1.0f);
    g_feat[g * 512 + 256 + t] = (cnt > 0.f) ? mx : 0.f;
}

// ---------------------------------------------------------------------------
// MLP head: out[g] = sigmoid(relu(g_feat @ fc1 + b1) @ fc2 + b2)
// One block (128 threads) per graph.
// ---------------------------------------------------------------------------
__global__ __launch_bounds__(128) void mlp_head(
    const float* __restrict__ g_feat,
    const float* __restrict__ fc1_w, const float* __restrict__ fc1_b,
    const float* __restrict__ fc2_w, const float* __restrict__ fc2_b,
    float* __restrict__ out)
{
    __shared__ float gf[512];
    __shared__ float partial[2];
    int g = blockIdx.x, t = threadIdx.x;
    for (int i = t; i < 512; i += 128) gf[i] = g_feat[g * 512 + i];
    __syncthreads();
    float acc = fc1_b[t];
    for (int i = 0; i < 512; ++i) acc += gf[i] * fc1_w[i * 128 + t];
    float h1 = fmaxf(acc, 0.f);
    float v = h1 * fc2_w[t];
    #pragma unroll
    for (int off = 32; off > 0; off >>= 1) v += __shfl_down(v, off);
    if ((t & 63) == 0) partial[t >> 6] = v;
    __syncthreads();
    if (t == 0) {
        float s = partial[0] + partial[1] + fc2_b[0];
        out[g] = 1.0f / (1.0f + expf(-s));
    }
}

// ---------------------------------------------------------------------------
// Launch
// ---------------------------------------------------------------------------
extern "C" void kernel_launch(void* const* d_in, const int* in_sizes, int n_in,
                              void* d_out, int out_size, void* d_ws, size_t ws_size,
                              hipStream_t stream) {
    const float* x          = (const float*)d_in[0];
    const int*   edge_index = (const int*)d_in[1];   // [2, E]: src then dst
    const int*   edge_attr  = (const int*)d_in[2];   // [E]
    const int*   batch      = (const int*)d_in[3];   // [N]
    const float* w0         = (const float*)d_in[4];   // [4,768,256]
    const float* root0      = (const float*)d_in[5];   // [768,256]
    const float* b0         = (const float*)d_in[6];   // [256]
    const float* w_rest     = (const float*)d_in[7];   // [5,4,256,256]
    const float* root_rest  = (const float*)d_in[8];   // [5,256,256]
    const float* b_rest     = (const float*)d_in[9];   // [5,256]
    const float* fc1_w      = (const float*)d_in[10];  // [512,128]
    const float* fc1_b      = (const float*)d_in[11];  // [128]
    const float* fc2_w      = (const float*)d_in[12];  // [128,1]
    const float* fc2_b      = (const float*)d_in[13];  // [1]
    float* out = (float*)d_out;

    const int* e_src = edge_index;
    const int* e_dst = edge_index + N_EDGES;

    // Workspace layout (floats)
    float* ws = (float*)d_ws;
    size_t off = 0;
    float* inv_cnt = ws + off; off += (size_t)N_REL * N_NODES;      // 240000
    float* h_a     = ws + off; off += (size_t)N_NODES * D_H;        // 15.36M
    float* h_b     = ws + off; off += (size_t)N_NODES * D_H;
    float* h_r     = ws + off; off += (size_t)N_NODES * D_H;
    float* g_feat  = ws + off; off += (size_t)N_GRAPHS * 512;

    // --- edge counts (fixed across layers) ---
    hipMemsetAsync(inv_cnt, 0, (size_t)N_REL * N_NODES * sizeof(float), stream);
    count_edges<<<cdiv(N_EDGES, 256), 256, 0, stream>>>(edge_attr, e_dst, inv_cnt, N_EDGES);
    invert_cnt<<<cdiv(N_REL * N_NODES, 256), 256, 0, stream>>>(inv_cnt, N_REL * N_NODES);

    const dim3 gemm_grid(cdiv(N_NODES, BM), D_H / BN);
    const int scat_grid = cdiv(N_EDGES, 4);
    const long relu_n4 = (long)N_NODES * D_H / 4;

    // --- layer 0 (K = 768) ---
    gemm_f32<<<gemm_grid, 256, 0, stream>>>(x, root0, b0, h_a, N_NODES, D_H, D_IN);
    for (int r = 0; r < N_REL; ++r) {
        gemm_f32<<<gemm_grid, 256, 0, stream>>>(x, w0 + (size_t)r * D_IN * D_H, nullptr,
                                                h_r, N_NODES, D_H, D_IN);
        scatter_mean_add<<<scat_grid, 256, 0, stream>>>(h_r, e_src, e_dst, edge_attr,
                                                        inv_cnt, h_a, N_EDGES, r);
    }
    relu_kernel<<<cdiv((int)relu_n4, 256), 256, 0, stream>>>(h_a, relu_n4);

    // --- layers 1..5 (K = 256) ---
    float* cur = h_a;
    float* nxt = h_b;
    for (int L = 1; L < N_LAYERS; ++L) {
        const float* root = root_rest + (size_t)(L - 1) * D_H * D_H;
        const float* bias = b_rest + (size_t)(L - 1) * D_H;
        gemm_f32<<<gemm_grid, 256, 0, stream>>>(cur, root, bias, nxt, N_NODES, D_H, D_H);
        for (int r = 0; r < N_REL; ++r) {
            const float* W = w_rest + ((size_t)(L - 1) * N_REL + r) * D_H * D_H;
            gemm_f32<<<gemm_grid, 256, 0, stream>>>(cur, W, nullptr, h_r, N_NODES, D_H, D_H);
            scatter_mean_add<<<scat_grid, 256, 0, stream>>>(h_r, e_src, e_dst, edge_attr,
                                                            inv_cnt, nxt, N_EDGES, r);
        }
        relu_kernel<<<cdiv((int)relu_n4, 256), 256, 0, stream>>>(nxt, relu_n4);
        float* tmp = cur; cur = nxt; nxt = tmp;
    }
    // after 5 swaps, final h is in `cur`

    // --- pooling + head ---
    pool_kernel<<<N_GRAPHS, 256, 0, stream>>>(cur, batch, g_feat);
    mlp_head<<<N_GRAPHS, 128, 0, stream>>>(g_feat, fc1_w, fc1_b, fc2_w, fc2_b, out);
}

// Round 2
// 1555.802 us; speedup vs baseline: 6.7437x; 6.7437x over previous
//
#include <hip/hip_runtime.h>
#include <hip/hip_bf16.h>

#define N_NODES  60000
#define N_EDGES  240000
#define N_REL    4
#define N_GRAPHS 128
#define D_IN     768
#define D_H      256
#define N_LAYERS 6
#define M_PAD    60032            // 469 * 128
#define N_TOT    1280             // 256 root + 4*256 msg

static inline int cdiv(int a, int b) { return (a + b - 1) / b; }

typedef __attribute__((ext_vector_type(8))) short short8;
typedef __attribute__((ext_vector_type(4))) float f32x4;

__device__ __forceinline__ float bf2f(unsigned short u) {
    union { unsigned int i; float f; } c; c.i = ((unsigned int)u) << 16; return c.f;
}
__device__ __forceinline__ unsigned short f2bf(float f) {
    union { float f; unsigned int i; } c; c.f = f;
    unsigned int i = c.i;
    unsigned int r = (i + 0x7FFFu + ((i >> 16) & 1u)) >> 16;   // RNE
    return (unsigned short)r;
}

__device__ __forceinline__ void gload16(const void* g, void* l) {
    __builtin_amdgcn_global_load_lds((const __attribute__((address_space(1))) void*)g,
                                     (__attribute__((address_space(3))) void*)l, 16, 0, 0);
}

// ---------------------------------------------------------------------------
// bf16 MFMA GEMM, B^T weights (m97 structure). A:[M,K] bf16, Bt:[1280,K] bf16.
// Root columns (n<256) -> out_root fp32 (+bias); msg columns -> out_msg bf16.
// M = M_PAD (multiple of 128), no bounds checks.
// ---------------------------------------------------------------------------
__global__ __launch_bounds__(256) void gemm_bf16(
    const unsigned short* __restrict__ A,
    const unsigned short* __restrict__ Bt,
    const float* __restrict__ bias,
    float* __restrict__ out_root,
    unsigned short* __restrict__ out_msg,
    int K)
{
    __shared__ unsigned short As[128 * 32];
    __shared__ unsigned short Bs[128 * 32];

    const int tid  = threadIdx.x;
    const int wave = tid >> 6, lane = tid & 63;
    const int bm = blockIdx.x * 128;
    const int bn = blockIdx.y * 128;
    const int wm = (wave & 1) * 64, wn = (wave >> 1) * 64;

    // staging: chunk c = it*256 + tid; row = c>>2, k-offset = (c&3)*8
    const int rowS = tid >> 2;
    const int kS   = (tid & 3) * 8;
    unsigned short* ldsA0 = As + (wave * 64) * 8;
    unsigned short* ldsA1 = As + (256 + wave * 64) * 8;
    unsigned short* ldsB0 = Bs + (wave * 64) * 8;
    unsigned short* ldsB1 = Bs + (256 + wave * 64) * 8;
    const unsigned short* gA0 = A  + (size_t)(bm + rowS) * K + kS;
    const unsigned short* gA1 = A  + (size_t)(bm + 64 + rowS) * K + kS;
    const unsigned short* gB0 = Bt + (size_t)(bn + rowS) * K + kS;
    const unsigned short* gB1 = Bt + (size_t)(bn + 64 + rowS) * K + kS;

    f32x4 acc[4][4] = {};

    const int fr = lane & 15;        // fragment m / n index
    const int fq = (lane >> 4) * 8;  // fragment k offset

    for (int k0 = 0; k0 < K; k0 += 32) {
        gload16(gA0 + k0, ldsA0);
        gload16(gA1 + k0, ldsA1);
        gload16(gB0 + k0, ldsB0);
        gload16(gB1 + k0, ldsB1);
        __syncthreads();

        short8 a[4], b[4];
        #pragma unroll
        for (int t = 0; t < 4; ++t) {
            a[t] = *(const short8*)&As[(wm + t * 16 + fr) * 32 + fq];
            b[t] = *(const short8*)&Bs[(wn + t * 16 + fr) * 32 + fq];
        }
        #pragma unroll
        for (int mt = 0; mt < 4; ++mt)
            #pragma unroll
            for (int nt = 0; nt < 4; ++nt)
                acc[mt][nt] = __builtin_amdgcn_mfma_f32_16x16x32_bf16(
                    a[mt], b[nt], acc[mt][nt], 0, 0, 0);
        __syncthreads();
    }

    const bool is_root = (bn < 256);   // block-uniform
    #pragma unroll
    for (int mt = 0; mt < 4; ++mt) {
        #pragma unroll
        for (int nt = 0; nt < 4; ++nt) {
            int col = bn + wn + nt * 16 + fr;
            #pragma unroll
            for (int r = 0; r < 4; ++r) {
                int row = bm + wm + mt * 16 + (lane >> 4) * 4 + r;
                float v = acc[mt][nt][r];
                if (is_root) out_root[(size_t)row * 256 + col] = v + bias[col];
                else         out_msg[(size_t)row * 1024 + (col - 256)] = f2bf(v);
            }
        }
    }
}

// ---------------------------------------------------------------------------
// Conversions / weight packing
// ---------------------------------------------------------------------------
__global__ void convert_x(const float* __restrict__ x, unsigned short* __restrict__ xb) {
    size_t i = ((size_t)blockIdx.x * 256 + threadIdx.x) * 4;
    if (i >= (size_t)M_PAD * D_IN) return;
    ushort4 o;
    if (i < (size_t)N_NODES * D_IN) {
        float4 v = *(const float4*)&x[i];
        o.x = f2bf(v.x); o.y = f2bf(v.y); o.z = f2bf(v.z); o.w = f2bf(v.w);
    } else {
        o.x = o.y = o.z = o.w = 0;
    }
    *(ushort4*)&xb[i] = o;
}

__global__ void pack_w0(const float* __restrict__ root0, const float* __restrict__ w0,
                        unsigned short* __restrict__ Wt0) {
    int idx = blockIdx.x * 256 + threadIdx.x;            // [1280*768], Wt0[n][k]
    if (idx >= N_TOT * D_IN) return;
    int k = idx % D_IN, n = idx / D_IN;
    float v = (n < 256) ? root0[k * 256 + n]
                        : w0[(((n >> 8) - 1) * D_IN + k) * 256 + (n & 255)];
    Wt0[idx] = f2bf(v);
}

__global__ void pack_wr(const float* __restrict__ root_rest, const float* __restrict__ w_rest,
                        unsigned short* __restrict__ WtR) {
    int idx = blockIdx.x * 256 + threadIdx.x;            // [5*1280*256], WtR[l][n][k]
    if (idx >= 5 * N_TOT * 256) return;
    int k = idx & 255; int t = idx >> 8; int n = t % N_TOT; int l = t / N_TOT;
    float v = (n < 256) ? root_rest[(l * 256 + k) * 256 + n]
                        : w_rest[((l * 4 + (n >> 8) - 1) * 256 + k) * 256 + (n & 255)];
    WtR[idx] = f2bf(v);
}

// ---------------------------------------------------------------------------
// CSR build (dst-grouped)
// ---------------------------------------------------------------------------
__global__ void deg_count(const int* __restrict__ dst, int* __restrict__ deg, int E) {
    int e = blockIdx.x * 256 + threadIdx.x;
    if (e < E) atomicAdd(&deg[dst[e]], 1);
}

__global__ __launch_bounds__(256) void block_sum(const int* __restrict__ deg,
                                                 int* __restrict__ bsum, int n) {
    __shared__ int s[256];
    int i = blockIdx.x * 256 + threadIdx.x;
    s[threadIdx.x] = (i < n) ? deg[i] : 0;
    __syncthreads();
    for (int o = 128; o > 0; o >>= 1) {
        if (threadIdx.x < o) s[threadIdx.x] += s[threadIdx.x + o];
        __syncthreads();
    }
    if (threadIdx.x == 0) bsum[blockIdx.x] = s[0];
}

__global__ __launch_bounds__(256) void scan_bsum(const int* __restrict__ bsum,
                                                 int* __restrict__ boff, int nb) {
    __shared__ int s[256];
    int t = threadIdx.x;
    int v0 = (t < nb) ? bsum[t] : 0;
    s[t] = v0;
    __syncthreads();
    for (int o = 1; o < 256; o <<= 1) {
        int v = (t >= o) ? s[t - o] : 0;
        __syncthreads();
        s[t] += v;
        __syncthreads();
    }
    if (t < nb) boff[t] = s[t] - v0;   // exclusive
}

__global__ __launch_bounds__(256) void block_scan_write(
    const int* __restrict__ deg, const int* __restrict__ boff,
    int* __restrict__ row_ptr, int* __restrict__ cursor, int n, int total) {
    __shared__ int s[256];
    int t = threadIdx.x;
    int i = blockIdx.x * 256 + t;
    int v = (i < n) ? deg[i] : 0;
    s[t] = v;
    __syncthreads();
    for (int o = 1; o < 256; o <<= 1) {
        int u = (t >= o) ? s[t - o] : 0;
        __syncthreads();
        s[t] += u;
        __syncthreads();
    }
    int excl = s[t] - v + boff[blockIdx.x];
    if (i < n) { row_ptr[i] = excl; cursor[i] = excl; }
    if (blockIdx.x == 0 && t == 0) row_ptr[n] = total;
}

__global__ void place_edges(const int* __restrict__ dst, int* __restrict__ cursor,
                            int* __restrict__ edge_ord, int E) {
    int e = blockIdx.x * 256 + threadIdx.x;
    if (e < E) { int p = atomicAdd(&cursor[dst[e]], 1); edge_ord[p] = e; }
}

// ---------------------------------------------------------------------------
// Aggregate: one wave per node. acc = root+bias part, += mean-scaled messages
// per relation, then ReLU + bf16 cast.
// ---------------------------------------------------------------------------
__global__ __launch_bounds__(256) void aggregate(
    const float* __restrict__ nxt_root, const unsigned short* __restrict__ h_msg,
    const int* __restrict__ row_ptr, const int* __restrict__ edge_ord,
    const int* __restrict__ e_src, const int* __restrict__ e_rel,
    unsigned short* __restrict__ h_out)
{
    int node = blockIdx.x * 4 + (threadIdx.x >> 6);
    if (node >= N_NODES) return;
    int lane = threadIdx.x & 63;
    int lo = row_ptr[node], hi = row_ptr[node + 1];

    float4 acc = *(const float4*)&nxt_root[(size_t)node * 256 + lane * 4];

    int c0 = 0, c1 = 0, c2 = 0, c3 = 0;
    for (int e = lo; e < hi; ++e) {
        int r = e_rel[edge_ord[e]];
        c0 += (r == 0); c1 += (r == 1); c2 += (r == 2); c3 += (r == 3);
    }
    float s0 = c0 ? 1.f / c0 : 1.f;
    float s1 = c1 ? 1.f / c1 : 1.f;
    float s2 = c2 ? 1.f / c2 : 1.f;
    float s3 = c3 ? 1.f / c3 : 1.f;

    for (int e = lo; e < hi; ++e) {
        int eid = edge_ord[e];
        int s = e_src[eid], r = e_rel[eid];
        float sc = (r == 0) ? s0 : (r == 1) ? s1 : (r == 2) ? s2 : s3;
        ushort4 m = *(const ushort4*)&h_msg[(size_t)s * 1024 + r * 256 + lane * 4];
        acc.x += bf2f(m.x) * sc;
        acc.y += bf2f(m.y) * sc;
        acc.z += bf2f(m.z) * sc;
        acc.w += bf2f(m.w) * sc;
    }
    ushort4 o;
    o.x = f2bf(fmaxf(acc.x, 0.f));
    o.y = f2bf(fmaxf(acc.y, 0.f));
    o.z = f2bf(fmaxf(acc.z, 0.f));
    o.w = f2bf(fmaxf(acc.w, 0.f));
    *(ushort4*)&h_out[(size_t)node * 256 + lane * 4] = o;
}

// ---------------------------------------------------------------------------
// Pooling (bf16 input) + MLP head
// ---------------------------------------------------------------------------
__global__ __launch_bounds__(256) void pool_kernel(
    const unsigned short* __restrict__ h, const int* __restrict__ batch,
    float* __restrict__ g_feat)
{
    int g = blockIdx.x;
    int t = threadIdx.x;
    __shared__ int s_lo, s_hi;
    if (t == 0) {
        int lo = 0, hi = N_NODES;
        while (lo < hi) { int m = (lo + hi) >> 1; if (batch[m] < g) lo = m + 1; else hi = m; }
        s_lo = lo;
        int lo2 = lo, hi2 = N_NODES;
        while (lo2 < hi2) { int m = (lo2 + hi2) >> 1; if (batch[m] < g + 1) lo2 = m + 1; else hi2 = m; }
        s_hi = lo2;
    }
    __syncthreads();
    int lo = s_lo, hi = s_hi;
    float sum = 0.f, mx = 0.f;   // h is post-ReLU
    for (int n = lo; n < hi; ++n) {
        float v = bf2f(h[(size_t)n * 256 + t]);
        sum += v;
        mx = fmaxf(mx, v);
    }
    float cnt = (float)(hi - lo);
    g_feat[g * 512 + t]       = sum / fmaxf(cnt, 1.0f);
    g_feat[g * 512 + 256 + t] = (cnt > 0.f) ? mx : 0.f;
}

__global__ __launch_bounds__(128) void mlp_head(
    const float* __restrict__ g_feat,
    const float* __restrict__ fc1_w, const float* __restrict__ fc1_b,
    const float* __restrict__ fc2_w, const float* __restrict__ fc2_b,
    float* __restrict__ out)
{
    __shared__ float gf[512];
    __shared__ float partial[2];
    int g = blockIdx.x, t = threadIdx.x;
    for (int i = t; i < 512; i += 128) gf[i] = g_feat[g * 512 + i];
    __syncthreads();
    float acc = fc1_b[t];
    for (int i = 0; i < 512; ++i) acc += gf[i] * fc1_w[i * 128 + t];
    float h1 = fmaxf(acc, 0.f);
    float v = h1 * fc2_w[t];
    #pragma unroll
    for (int off = 32; off > 0; off >>= 1) v += __shfl_down(v, off);
    if ((t & 63) == 0) partial[t >> 6] = v;
    __syncthreads();
    if (t == 0) {
        float s = partial[0] + partial[1] + fc2_b[0];
        out[g] = 1.0f / (1.0f + expf(-s));
    }
}

// ---------------------------------------------------------------------------
// Launch
// ---------------------------------------------------------------------------
extern "C" void kernel_launch(void* const* d_in, const int* in_sizes, int n_in,
                              void* d_out, int out_size, void* d_ws, size_t ws_size,
                              hipStream_t stream) {
    const float* x          = (const float*)d_in[0];
    const int*   edge_index = (const int*)d_in[1];
    const int*   edge_attr  = (const int*)d_in[2];
    const int*   batch      = (const int*)d_in[3];
    const float* w0         = (const float*)d_in[4];
    const float* root0      = (const float*)d_in[5];
    const float* b0         = (const float*)d_in[6];
    const float* w_rest     = (const float*)d_in[7];
    const float* root_rest  = (const float*)d_in[8];
    const float* b_rest     = (const float*)d_in[9];
    const float* fc1_w      = (const float*)d_in[10];
    const float* fc1_b      = (const float*)d_in[11];
    const float* fc2_w      = (const float*)d_in[12];
    const float* fc2_b      = (const float*)d_in[13];
    float* out = (float*)d_out;

    const int* e_src = edge_index;
    const int* e_dst = edge_index + N_EDGES;

    // Workspace layout (bytes, 256-aligned)
    char* p = (char*)d_ws;
    auto alloc = [&](size_t bytes) { char* q = p; p += (bytes + 255) & ~(size_t)255; return q; };
    unsigned short* x_bf   = (unsigned short*)alloc((size_t)M_PAD * D_IN * 2);   // 92.2 MB
    unsigned short* h_bf   = (unsigned short*)alloc((size_t)M_PAD * 256 * 2);    // 30.7 MB
    float*          nxt    = (float*)alloc((size_t)M_PAD * 256 * 4);             // 61.5 MB
    unsigned short* h_msg  = (unsigned short*)alloc((size_t)M_PAD * 1024 * 2);   // 123 MB
    unsigned short* Wt0    = (unsigned short*)alloc((size_t)N_TOT * D_IN * 2);   // 2.0 MB
    unsigned short* WtR    = (unsigned short*)alloc((size_t)5 * N_TOT * 256 * 2);// 3.3 MB
    float*          g_feat = (float*)alloc((size_t)N_GRAPHS * 512 * 4);
    int*            deg    = (int*)alloc((size_t)N_NODES * 4);
    int*            row_ptr= (int*)alloc((size_t)(N_NODES + 1) * 4);
    int*            cursor = (int*)alloc((size_t)N_NODES * 4);
    int*            bsum   = (int*)alloc(256 * 4);
    int*            boff   = (int*)alloc(256 * 4);
    int*            edge_ord=(int*)alloc((size_t)N_EDGES * 4);

    const int nscan = cdiv(N_NODES, 256);   // 235

    // --- prep: conversions, weight pack, CSR ---
    hipMemsetAsync(deg, 0, (size_t)N_NODES * 4, stream);
    hipMemsetAsync(h_bf, 0, (size_t)M_PAD * 256 * 2, stream);
    convert_x<<<cdiv(M_PAD * D_IN / 4, 256), 256, 0, stream>>>(x, x_bf);
    pack_w0<<<cdiv(N_TOT * D_IN, 256), 256, 0, stream>>>(root0, w0, Wt0);
    pack_wr<<<cdiv(5 * N_TOT * 256, 256), 256, 0, stream>>>(root_rest, w_rest, WtR);
    deg_count<<<cdiv(N_EDGES, 256), 256, 0, stream>>>(e_dst, deg, N_EDGES);
    block_sum<<<nscan, 256, 0, stream>>>(deg, bsum, N_NODES);
    scan_bsum<<<1, 256, 0, stream>>>(bsum, boff, nscan);
    block_scan_write<<<nscan, 256, 0, stream>>>(deg, boff, row_ptr, cursor, N_NODES, N_EDGES);
    place_edges<<<cdiv(N_EDGES, 256), 256, 0, stream>>>(e_dst, cursor, edge_ord, N_EDGES);

    const dim3 gemm_grid(M_PAD / 128, N_TOT / 128);
    const int agg_grid = cdiv(N_NODES, 4);

    // --- layer 0 (K=768) ---
    gemm_bf16<<<gemm_grid, 256, 0, stream>>>(x_bf, Wt0, b0, nxt, h_msg, D_IN);
    aggregate<<<agg_grid, 256, 0, stream>>>(nxt, h_msg, row_ptr, edge_ord,
                                            e_src, edge_attr, h_bf);
    // --- layers 1..5 (K=256) ---
    for (int L = 1; L < N_LAYERS; ++L) {
        const unsigned short* Wt = WtR + (size_t)(L - 1) * N_TOT * 256;
        const float* bias = b_rest + (size_t)(L - 1) * 256;
        gemm_bf16<<<gemm_grid, 256, 0, stream>>>(h_bf, Wt, bias, nxt, h_msg, D_H);
        aggregate<<<agg_grid, 256, 0, stream>>>(nxt, h_msg, row_ptr, edge_ord,
                                                e_src, edge_attr, h_bf);
    }

    // --- pooling + head ---
    pool_kernel<<<N_GRAPHS, 256, 0, stream>>>(h_bf, batch, g_feat);
    mlp_head<<<N_GRAPHS, 128, 0, stream>>>(g_feat, fc1_w, fc1_b, fc2_w, fc2_b, out);
}

// Round 3
// 1242.618 us; speedup vs baseline: 8.4433x; 1.2520x over previous
//
#include <hip/hip_runtime.h>
#include <hip/hip_bf16.h>

#define N_NODES  60000
#define N_EDGES  240000
#define N_REL    4
#define N_GRAPHS 128
#define D_IN     768
#define D_H      256
#define N_LAYERS 6
#define M_PAD    60032            // 469 * 128
#define N_TOT    1280             // 256 root + 4*256 msg (layer 0)
#define LDW      1280             // row stride of A' buffers (4*256 means | 256 h)

static inline int cdiv(int a, int b) { return (a + b - 1) / b; }

typedef __attribute__((ext_vector_type(8))) short short8;
typedef __attribute__((ext_vector_type(4))) float f32x4;

__device__ __forceinline__ float bf2f(unsigned short u) {
    union { unsigned int i; float f; } c; c.i = ((unsigned int)u) << 16; return c.f;
}
__device__ __forceinline__ unsigned short f2bf(float f) {
    union { float f; unsigned int i; } c; c.f = f;
    unsigned int i = c.i;
    unsigned int r = (i + 0x7FFFu + ((i >> 16) & 1u)) >> 16;   // RNE
    return (unsigned short)r;
}

__device__ __forceinline__ void gload16(const void* g, void* l) {
    __builtin_amdgcn_global_load_lds((const __attribute__((address_space(1))) void*)g,
                                     (__attribute__((address_space(3))) void*)l, 16, 0, 0);
}

// ---------------------------------------------------------------------------
// bf16 MFMA GEMM: A[M_PAD,K] bf16 @ Bt[N_cols,K]^T -> bf16 out.
// BM=128, BN=256, BK=32, 512 threads (8 waves, 2m x 4n, 64x64 wave tiles).
// LDS chunks XOR-swizzled so ds_read_b128 fragment loads are 2-way (free).
// Epilogue: +bias[col], optional ReLU, bf16 store at out[row*ldOut+colOff+col].
// ---------------------------------------------------------------------------
__global__ __launch_bounds__(512) void gemm_bf16(
    const unsigned short* __restrict__ A,
    const unsigned short* __restrict__ Bt,
    const float* __restrict__ bias,
    unsigned short* __restrict__ out,
    int K, int ldOut, int colOff, int relu)
{
    __shared__ unsigned short As[128 * 32];
    __shared__ unsigned short Bs[256 * 32];

    const int tid  = threadIdx.x;
    const int wave = tid >> 6, lane = tid & 63;
    const int bm = blockIdx.x * 128;
    const int bn = blockIdx.y * 256;
    const int wm = (wave & 1) * 64, wn = (wave >> 1) * 64;

    // Staging: 24 x 1KB global_load_lds per K-step; wave w issues insts 3w..3w+2.
    // Inst g covers 16 rows (g<8: A rows 16g.. ; g>=8: B rows 16(g-8)..).
    // Lane l -> local row lr=l>>2, chunk slot c=l&3 (HW: LDS dst = base+16B*l).
    // Swizzle: slot c holds global chunk c ^ ((lr ^ (lr>>2)) & 3).
    const int lr = lane >> 2;
    const int kg = ((lane & 3) ^ ((lr ^ (lr >> 2)) & 3)) * 8;   // shorts
    const unsigned short* gsrc[3];
    unsigned short* ldst[3];
    #pragma unroll
    for (int j = 0; j < 3; ++j) {
        int g = wave * 3 + j;
        if (g < 8) {
            gsrc[j] = A + (size_t)(bm + g * 16 + lr) * K + kg;
            ldst[j] = As + g * 16 * 32;
        } else {
            gsrc[j] = Bt + (size_t)(bn + (g - 8) * 16 + lr) * K + kg;
            ldst[j] = Bs + (g - 8) * 16 * 32;
        }
    }

    f32x4 acc[4][4] = {};
    const int fr = lane & 15;
    // fragment k-chunk q = lane>>4; stored at slot q ^ s(row), s = (fr^(fr>>2))&3
    const int qsw = (((lane >> 4) ^ fr ^ (fr >> 2)) & 3) * 8;

    for (int k0 = 0; k0 < K; k0 += 32) {
        gload16(gsrc[0] + k0, ldst[0]);
        gload16(gsrc[1] + k0, ldst[1]);
        gload16(gsrc[2] + k0, ldst[2]);
        __syncthreads();

        short8 a[4], b[4];
        #pragma unroll
        for (int t = 0; t < 4; ++t) {
            a[t] = *(const short8*)&As[(wm + t * 16 + fr) * 32 + qsw];
            b[t] = *(const short8*)&Bs[(wn + t * 16 + fr) * 32 + qsw];
        }
        #pragma unroll
        for (int mt = 0; mt < 4; ++mt)
            #pragma unroll
            for (int nt = 0; nt < 4; ++nt)
                acc[mt][nt] = __builtin_amdgcn_mfma_f32_16x16x32_bf16(
                    a[mt], b[nt], acc[mt][nt], 0, 0, 0);
        __syncthreads();
    }

    #pragma unroll
    for (int mt = 0; mt < 4; ++mt) {
        #pragma unroll
        for (int nt = 0; nt < 4; ++nt) {
            int col = bn + wn + nt * 16 + fr;
            float bv = bias[col];
            #pragma unroll
            for (int r = 0; r < 4; ++r) {
                int row = bm + wm + mt * 16 + ((lane >> 4) << 2) + r;
                float v = acc[mt][nt][r] + bv;
                if (relu) v = fmaxf(v, 0.f);
                out[(size_t)row * ldOut + colOff + col] = f2bf(v);
            }
        }
    }
}

// ---------------------------------------------------------------------------
// Conversions / weight packing
// ---------------------------------------------------------------------------
__global__ void convert_x(const float* __restrict__ x, unsigned short* __restrict__ xb) {
    size_t i = ((size_t)blockIdx.x * 256 + threadIdx.x) * 4;
    if (i >= (size_t)M_PAD * D_IN) return;
    ushort4 o;
    if (i < (size_t)N_NODES * D_IN) {
        float4 v = *(const float4*)&x[i];
        o.x = f2bf(v.x); o.y = f2bf(v.y); o.z = f2bf(v.z); o.w = f2bf(v.w);
    } else {
        o.x = o.y = o.z = o.w = 0;
    }
    *(ushort4*)&xb[i] = o;
}

// Wt0[n][k], n in [0,1280), k in [0,768): n<256 -> root0[k][n], else w0[(n>>8)-1][k][n&255]
__global__ void pack_w0(const float* __restrict__ root0, const float* __restrict__ w0,
                        unsigned short* __restrict__ Wt0) {
    int idx = blockIdx.x * 256 + threadIdx.x;
    if (idx >= N_TOT * D_IN) return;
    int k = idx % D_IN, n = idx / D_IN;
    float v = (n < 256) ? root0[k * 256 + n]
                        : w0[(((n >> 8) - 1) * D_IN + k) * 256 + (n & 255)];
    Wt0[idx] = f2bf(v);
}

// WtR[l][n][k], n in [0,256), k in [0,1280):
//  k<1024 -> w_rest[l][k>>8][k&255][n];  k>=1024 -> root_rest[l][k-1024][n]
__global__ void pack_wr(const float* __restrict__ root_rest, const float* __restrict__ w_rest,
                        unsigned short* __restrict__ WtR) {
    int idx = blockIdx.x * 256 + threadIdx.x;
    if (idx >= 5 * 256 * LDW) return;
    int k = idx % LDW; int t = idx / LDW; int n = t & 255; int l = t >> 8;
    float v = (k < 1024)
        ? w_rest[(((l * 4 + (k >> 8)) * 256) + (k & 255)) * 256 + n]
        : root_rest[(l * 256 + (k - 1024)) * 256 + n];
    WtR[idx] = f2bf(v);
}

__global__ void build_bias(const float* __restrict__ b0, float* __restrict__ eb) {
    int i = blockIdx.x * 256 + threadIdx.x;
    if (i < N_TOT) eb[i] = (i < 256) ? b0[i] : 0.f;
}

// ---------------------------------------------------------------------------
// CSR build (dst-grouped), per-(node,rel) inverse counts, packed (src|rel<<16)
// ---------------------------------------------------------------------------
__global__ void deg_count(const int* __restrict__ dst, int* __restrict__ deg, int E) {
    int e = blockIdx.x * 256 + threadIdx.x;
    if (e < E) atomicAdd(&deg[dst[e]], 1);
}

__global__ void count4(const int* __restrict__ dst, const int* __restrict__ rel,
                       float* __restrict__ cnt4, int E) {
    int e = blockIdx.x * 256 + threadIdx.x;
    if (e < E) atomicAdd(&cnt4[dst[e] * 4 + rel[e]], 1.0f);
}

__global__ void invert4(float* __restrict__ c, int n) {
    int i = blockIdx.x * 256 + threadIdx.x;
    if (i < n) c[i] = 1.0f / fmaxf(c[i], 1.0f);
}

__global__ __launch_bounds__(256) void block_sum(const int* __restrict__ deg,
                                                 int* __restrict__ bsum, int n) {
    __shared__ int s[256];
    int i = blockIdx.x * 256 + threadIdx.x;
    s[threadIdx.x] = (i < n) ? deg[i] : 0;
    __syncthreads();
    for (int o = 128; o > 0; o >>= 1) {
        if (threadIdx.x < o) s[threadIdx.x] += s[threadIdx.x + o];
        __syncthreads();
    }
    if (threadIdx.x == 0) bsum[blockIdx.x] = s[0];
}

__global__ __launch_bounds__(256) void scan_bsum(const int* __restrict__ bsum,
                                                 int* __restrict__ boff, int nb) {
    __shared__ int s[256];
    int t = threadIdx.x;
    int v0 = (t < nb) ? bsum[t] : 0;
    s[t] = v0;
    __syncthreads();
    for (int o = 1; o < 256; o <<= 1) {
        int v = (t >= o) ? s[t - o] : 0;
        __syncthreads();
        s[t] += v;
        __syncthreads();
    }
    if (t < nb) boff[t] = s[t] - v0;   // exclusive
}

__global__ __launch_bounds__(256) void block_scan_write(
    const int* __restrict__ deg, const int* __restrict__ boff,
    int* __restrict__ row_ptr, int* __restrict__ cursor, int n, int total) {
    __shared__ int s[256];
    int t = threadIdx.x;
    int i = blockIdx.x * 256 + t;
    int v = (i < n) ? deg[i] : 0;
    s[t] = v;
    __syncthreads();
    for (int o = 1; o < 256; o <<= 1) {
        int u = (t >= o) ? s[t - o] : 0;
        __syncthreads();
        s[t] += u;
        __syncthreads();
    }
    int excl = s[t] - v + boff[blockIdx.x];
    if (i < n) { row_ptr[i] = excl; cursor[i] = excl; }
    if (blockIdx.x == 0 && t == 0) row_ptr[n] = total;
}

__global__ void place_edges(const int* __restrict__ dst, const int* __restrict__ src,
                            const int* __restrict__ rel, int* __restrict__ cursor,
                            int* __restrict__ edge_sr, int E) {
    int e = blockIdx.x * 256 + threadIdx.x;
    if (e < E) {
        int p = atomicAdd(&cursor[dst[e]], 1);
        edge_sr[p] = src[e] | (rel[e] << 16);   // src < 65536
    }
}

// ---------------------------------------------------------------------------
// Layer-0 aggregate (transform-first consume): one wave per node.
// acc = root(+bias) from msg0 cols 0..255; += inv*msg_r[src]; ReLU; bf16 ->
// h-slot (cols 1024..1279) of A'.
// ---------------------------------------------------------------------------
__global__ __launch_bounds__(256) void aggregate0(
    const unsigned short* __restrict__ msg0,
    const int* __restrict__ row_ptr, const int* __restrict__ edge_sr,
    const float* __restrict__ inv4,
    unsigned short* __restrict__ h_out)
{
    int node = blockIdx.x * 4 + (threadIdx.x >> 6);
    if (node >= N_NODES) return;
    int lane = threadIdx.x & 63;
    int lo = row_ptr[node], hi = row_ptr[node + 1];
    float4 iv = *(const float4*)&inv4[node * 4];

    ushort4 rt = *(const ushort4*)&msg0[(size_t)node * LDW + lane * 4];
    float4 acc = make_float4(bf2f(rt.x), bf2f(rt.y), bf2f(rt.z), bf2f(rt.w));

    for (int e = lo; e < hi; ++e) {
        int sr = edge_sr[e];
        int s = sr & 0xFFFF, r = sr >> 16;
        float f = (r == 0) ? iv.x : (r == 1) ? iv.y : (r == 2) ? iv.z : iv.w;
        ushort4 m = *(const ushort4*)&msg0[(size_t)s * LDW + 256 + (r << 8) + lane * 4];
        acc.x += bf2f(m.x) * f;
        acc.y += bf2f(m.y) * f;
        acc.z += bf2f(m.z) * f;
        acc.w += bf2f(m.w) * f;
    }
    ushort4 o;
    o.x = f2bf(fmaxf(acc.x, 0.f));
    o.y = f2bf(fmaxf(acc.y, 0.f));
    o.z = f2bf(fmaxf(acc.z, 0.f));
    o.w = f2bf(fmaxf(acc.w, 0.f));
    *(ushort4*)&h_out[(size_t)node * LDW + 1024 + lane * 4] = o;
}

// ---------------------------------------------------------------------------
// Per-relation mean gather: reads h from buf cols 1024..1279, writes means to
// buf cols 0..1023 (same buffer). One wave per node, 4 fp32x4 accumulators.
// ---------------------------------------------------------------------------
__global__ __launch_bounds__(256) void agg_means(
    unsigned short* __restrict__ buf,
    const int* __restrict__ row_ptr, const int* __restrict__ edge_sr,
    const float* __restrict__ inv4)
{
    int node = blockIdx.x * 4 + (threadIdx.x >> 6);
    if (node >= N_NODES) return;
    int lane = threadIdx.x & 63;
    int lo = row_ptr[node], hi = row_ptr[node + 1];
    float4 iv = *(const float4*)&inv4[node * 4];

    float4 a0 = make_float4(0, 0, 0, 0), a1 = a0, a2 = a0, a3 = a0;
    for (int e = lo; e < hi; ++e) {
        int sr = edge_sr[e];
        int s = sr & 0xFFFF, r = sr >> 16;   // wave-uniform branch below
        ushort4 m = *(const ushort4*)&buf[(size_t)s * LDW + 1024 + lane * 4];
        float4 v = make_float4(bf2f(m.x), bf2f(m.y), bf2f(m.z), bf2f(m.w));
        if (r == 0)      { a0.x += v.x; a0.y += v.y; a0.z += v.z; a0.w += v.w; }
        else if (r == 1) { a1.x += v.x; a1.y += v.y; a1.z += v.z; a1.w += v.w; }
        else if (r == 2) { a2.x += v.x; a2.y += v.y; a2.z += v.z; a2.w += v.w; }
        else             { a3.x += v.x; a3.y += v.y; a3.z += v.z; a3.w += v.w; }
    }
    size_t base = (size_t)node * LDW + lane * 4;
    ushort4 o;
    o.x = f2bf(a0.x * iv.x); o.y = f2bf(a0.y * iv.x); o.z = f2bf(a0.z * iv.x); o.w = f2bf(a0.w * iv.x);
    *(ushort4*)&buf[base + 0]   = o;
    o.x = f2bf(a1.x * iv.y); o.y = f2bf(a1.y * iv.y); o.z = f2bf(a1.z * iv.y); o.w = f2bf(a1.w * iv.y);
    *(ushort4*)&buf[base + 256] = o;
    o.x = f2bf(a2.x * iv.z); o.y = f2bf(a2.y * iv.z); o.z = f2bf(a2.z * iv.z); o.w = f2bf(a2.w * iv.z);
    *(ushort4*)&buf[base + 512] = o;
    o.x = f2bf(a3.x * iv.w); o.y = f2bf(a3.y * iv.w); o.z = f2bf(a3.z * iv.w); o.w = f2bf(a3.w * iv.w);
    *(ushort4*)&buf[base + 768] = o;
}

// ---------------------------------------------------------------------------
// Pooling (bf16 h at stride LDW, cols 1024..1279) + MLP head
// ---------------------------------------------------------------------------
__global__ __launch_bounds__(256) void pool_kernel(
    const unsigned short* __restrict__ h, const int* __restrict__ batch,
    float* __restrict__ g_feat)
{
    int g = blockIdx.x;
    int t = threadIdx.x;
    __shared__ int s_lo, s_hi;
    if (t == 0) {
        int lo = 0, hi = N_NODES;
        while (lo < hi) { int m = (lo + hi) >> 1; if (batch[m] < g) lo = m + 1; else hi = m; }
        s_lo = lo;
        int lo2 = lo, hi2 = N_NODES;
        while (lo2 < hi2) { int m = (lo2 + hi2) >> 1; if (batch[m] < g + 1) lo2 = m + 1; else hi2 = m; }
        s_hi = lo2;
    }
    __syncthreads();
    int lo = s_lo, hi = s_hi;
    float sum = 0.f, mx = 0.f;   // post-ReLU
    for (int n = lo; n < hi; ++n) {
        float v = bf2f(h[(size_t)n * LDW + 1024 + t]);
        sum += v;
        mx = fmaxf(mx, v);
    }
    float cnt = (float)(hi - lo);
    g_feat[g * 512 + t]       = sum / fmaxf(cnt, 1.0f);
    g_feat[g * 512 + 256 + t] = (cnt > 0.f) ? mx : 0.f;
}

__global__ __launch_bounds__(128) void mlp_head(
    const float* __restrict__ g_feat,
    const float* __restrict__ fc1_w, const float* __restrict__ fc1_b,
    const float* __restrict__ fc2_w, const float* __restrict__ fc2_b,
    float* __restrict__ out)
{
    __shared__ float gf[512];
    __shared__ float partial[2];
    int g = blockIdx.x, t = threadIdx.x;
    for (int i = t; i < 512; i += 128) gf[i] = g_feat[g * 512 + i];
    __syncthreads();
    float acc = fc1_b[t];
    for (int i = 0; i < 512; ++i) acc += gf[i] * fc1_w[i * 128 + t];
    float h1 = fmaxf(acc, 0.f);
    float v = h1 * fc2_w[t];
    #pragma unroll
    for (int off = 32; off > 0; off >>= 1) v += __shfl_down(v, off);
    if ((t & 63) == 0) partial[t >> 6] = v;
    __syncthreads();
    if (t == 0) {
        float s = partial[0] + partial[1] + fc2_b[0];
        out[g] = 1.0f / (1.0f + expf(-s));
    }
}

// ---------------------------------------------------------------------------
// Launch
// ---------------------------------------------------------------------------
extern "C" void kernel_launch(void* const* d_in, const int* in_sizes, int n_in,
                              void* d_out, int out_size, void* d_ws, size_t ws_size,
                              hipStream_t stream) {
    const float* x          = (const float*)d_in[0];
    const int*   edge_index = (const int*)d_in[1];
    const int*   edge_attr  = (const int*)d_in[2];
    const int*   batch      = (const int*)d_in[3];
    const float* w0         = (const float*)d_in[4];
    const float* root0      = (const float*)d_in[5];
    const float* b0         = (const float*)d_in[6];
    const float* w_rest     = (const float*)d_in[7];
    const float* root_rest  = (const float*)d_in[8];
    const float* b_rest     = (const float*)d_in[9];
    const float* fc1_w      = (const float*)d_in[10];
    const float* fc1_b      = (const float*)d_in[11];
    const float* fc2_w      = (const float*)d_in[12];
    const float* fc2_b      = (const float*)d_in[13];
    float* out = (float*)d_out;

    const int* e_src = edge_index;
    const int* e_dst = edge_index + N_EDGES;

    char* p = (char*)d_ws;
    auto alloc = [&](size_t bytes) { char* q = p; p += (bytes + 255) & ~(size_t)255; return q; };
    unsigned short* x_bf   = (unsigned short*)alloc((size_t)M_PAD * D_IN * 2);   // 92 MB
    unsigned short* bufA   = (unsigned short*)alloc((size_t)M_PAD * LDW * 2);    // 154 MB
    unsigned short* bufB   = (unsigned short*)alloc((size_t)M_PAD * LDW * 2);    // 154 MB
    unsigned short* Wt0    = (unsigned short*)alloc((size_t)N_TOT * D_IN * 2);
    unsigned short* WtR    = (unsigned short*)alloc((size_t)5 * 256 * LDW * 2);
    float*          ebias  = (float*)alloc(N_TOT * 4);
    float*          inv4   = (float*)alloc((size_t)N_NODES * 4 * 4);
    float*          g_feat = (float*)alloc((size_t)N_GRAPHS * 512 * 4);
    int*            deg    = (int*)alloc((size_t)N_NODES * 4);
    int*            row_ptr= (int*)alloc((size_t)(N_NODES + 1) * 4);
    int*            cursor = (int*)alloc((size_t)N_NODES * 4);
    int*            bsum   = (int*)alloc(256 * 4);
    int*            boff   = (int*)alloc(256 * 4);
    int*            edge_sr= (int*)alloc((size_t)N_EDGES * 4);

    const int nscan = cdiv(N_NODES, 256);   // 235

    // --- prep ---
    hipMemsetAsync(deg, 0, (size_t)N_NODES * 4, stream);
    hipMemsetAsync(inv4, 0, (size_t)N_NODES * 16, stream);
    convert_x<<<cdiv(M_PAD * D_IN / 4, 256), 256, 0, stream>>>(x, x_bf);
    pack_w0<<<cdiv(N_TOT * D_IN, 256), 256, 0, stream>>>(root0, w0, Wt0);
    pack_wr<<<cdiv(5 * 256 * LDW, 256), 256, 0, stream>>>(root_rest, w_rest, WtR);
    build_bias<<<cdiv(N_TOT, 256), 256, 0, stream>>>(b0, ebias);
    deg_count<<<cdiv(N_EDGES, 256), 256, 0, stream>>>(e_dst, deg, N_EDGES);
    count4<<<cdiv(N_EDGES, 256), 256, 0, stream>>>(e_dst, edge_attr, inv4, N_EDGES);
    invert4<<<cdiv(N_NODES * 4, 256), 256, 0, stream>>>(inv4, N_NODES * 4);
    block_sum<<<nscan, 256, 0, stream>>>(deg, bsum, N_NODES);
    scan_bsum<<<1, 256, 0, stream>>>(bsum, boff, nscan);
    block_scan_write<<<nscan, 256, 0, stream>>>(deg, boff, row_ptr, cursor, N_NODES, N_EDGES);
    place_edges<<<cdiv(N_EDGES, 256), 256, 0, stream>>>(e_dst, e_src, edge_attr, cursor,
                                                        edge_sr, N_EDGES);

    const int agg_grid = cdiv(N_NODES, 4);

    // --- layer 0 (transform-first): msg0 = [x@root0+b | x@W0_r], all bf16 -> bufB
    gemm_bf16<<<dim3(M_PAD / 128, N_TOT / 256), 512, 0, stream>>>(
        x_bf, Wt0, ebias, bufB, D_IN, LDW, 0, 0);
    aggregate0<<<agg_grid, 256, 0, stream>>>(bufB, row_ptr, edge_sr, inv4, bufA);

    // --- layers 1..5 (aggregate-first): means into cur, GEMM K=1280 -> nxt h-slot
    unsigned short* cur = bufA;
    unsigned short* nxt = bufB;
    for (int L = 1; L < N_LAYERS; ++L) {
        agg_means<<<agg_grid, 256, 0, stream>>>(cur, row_ptr, edge_sr, inv4);
        gemm_bf16<<<dim3(M_PAD / 128, 1), 512, 0, stream>>>(
            cur, WtR + (size_t)(L - 1) * 256 * LDW, b_rest + (size_t)(L - 1) * 256,
            nxt, LDW, LDW, 1024, 1);
        unsigned short* t = cur; cur = nxt; nxt = t;
    }
    // h_6 is in cur's h-slot (L=5 wrote into bufB when starting from bufA)

    pool_kernel<<<N_GRAPHS, 256, 0, stream>>>(cur, batch, g_feat);
    mlp_head<<<N_GRAPHS, 128, 0, stream>>>(g_feat, fc1_w, fc1_b, fc2_w, fc2_b, out);
}

// Round 4
// 1208.225 us; speedup vs baseline: 8.6837x; 1.0285x over previous
//
#include <hip/hip_runtime.h>
#include <hip/hip_bf16.h>

#define N_NODES  60000
#define N_EDGES  240000
#define N_REL    4
#define N_GRAPHS 128
#define D_IN     768
#define D_H      256
#define N_LAYERS 6
#define M_PAD    60032            // 469 * 128
#define N_TOT    1280             // L0: 256 root + 4*256 msg
#define BM_L     64               // fused layer: dst rows per block
#define LDM      264              // mean tile row stride (256 + 8 shorts = +16B pad)

static inline int cdiv(int a, int b) { return (a + b - 1) / b; }

typedef __attribute__((ext_vector_type(8))) short short8;
typedef __attribute__((ext_vector_type(4))) float f32x4;

__device__ __forceinline__ float bf2f(unsigned short u) {
    union { unsigned int i; float f; } c; c.i = ((unsigned int)u) << 16; return c.f;
}
__device__ __forceinline__ float bflo(unsigned int u) {
    union { unsigned int i; float f; } c; c.i = u << 16; return c.f;
}
__device__ __forceinline__ float bfhi(unsigned int u) {
    union { unsigned int i; float f; } c; c.i = u & 0xffff0000u; return c.f;
}
__device__ __forceinline__ unsigned short f2bf(float f) {
    union { float f; unsigned int i; } c; c.f = f;
    unsigned int i = c.i;
    unsigned int r = (i + 0x7FFFu + ((i >> 16) & 1u)) >> 16;   // RNE
    return (unsigned short)r;
}

__device__ __forceinline__ void gload16(const void* g, void* l) {
    __builtin_amdgcn_global_load_lds((const __attribute__((address_space(1))) void*)g,
                                     (__attribute__((address_space(3))) void*)l, 16, 0, 0);
}

// ---------------------------------------------------------------------------
// Layer-0 GEMM (transform-first): A[M_PAD,768] bf16 @ Wt0[1280,768]^T.
// grid(5, 469): col blocks of one row-block adjacent -> A row-slice L2/L3 reuse.
// bn==0 -> out_root (ld 256, +bias); else out_msg (ld 1024, col-256).
// ---------------------------------------------------------------------------
__global__ __launch_bounds__(512) void gemm_l0(
    const unsigned short* __restrict__ A,
    const unsigned short* __restrict__ Bt,
    const float* __restrict__ bias,
    unsigned short* __restrict__ out_root,
    unsigned short* __restrict__ out_msg,
    int K)
{
    __shared__ unsigned short As[128 * 32];
    __shared__ unsigned short Bs[256 * 32];

    const int tid  = threadIdx.x;
    const int wave = tid >> 6, lane = tid & 63;
    const int bn = blockIdx.x * 256;
    const int bm = blockIdx.y * 128;
    const int wm = (wave & 1) * 64, wn = (wave >> 1) * 64;

    const int lr = lane >> 2;
    const int kg = ((lane & 3) ^ ((lr ^ (lr >> 2)) & 3)) * 8;   // swizzled k-chunk
    const unsigned short* gsrc[3];
    unsigned short* ldst[3];
    #pragma unroll
    for (int j = 0; j < 3; ++j) {
        int g = wave * 3 + j;
        if (g < 8) {
            gsrc[j] = A + (size_t)(bm + g * 16 + lr) * K + kg;
            ldst[j] = As + g * 16 * 32;
        } else {
            gsrc[j] = Bt + (size_t)(bn + (g - 8) * 16 + lr) * K + kg;
            ldst[j] = Bs + (g - 8) * 16 * 32;
        }
    }

    f32x4 acc[4][4] = {};
    const int fr = lane & 15;
    const int qsw = (((lane >> 4) ^ fr ^ (fr >> 2)) & 3) * 8;

    for (int k0 = 0; k0 < K; k0 += 32) {
        gload16(gsrc[0] + k0, ldst[0]);
        gload16(gsrc[1] + k0, ldst[1]);
        gload16(gsrc[2] + k0, ldst[2]);
        __syncthreads();

        short8 a[4], b[4];
        #pragma unroll
        for (int t = 0; t < 4; ++t) {
            a[t] = *(const short8*)&As[(wm + t * 16 + fr) * 32 + qsw];
            b[t] = *(const short8*)&Bs[(wn + t * 16 + fr) * 32 + qsw];
        }
        #pragma unroll
        for (int mt = 0; mt < 4; ++mt)
            #pragma unroll
            for (int nt = 0; nt < 4; ++nt)
                acc[mt][nt] = __builtin_amdgcn_mfma_f32_16x16x32_bf16(
                    a[mt], b[nt], acc[mt][nt], 0, 0, 0);
        __syncthreads();
    }

    const bool is_root = (bn == 0);   // block-uniform
    #pragma unroll
    for (int mt = 0; mt < 4; ++mt) {
        #pragma unroll
        for (int nt = 0; nt < 4; ++nt) {
            int col = bn + wn + nt * 16 + fr;
            float bv = bias[col];
            #pragma unroll
            for (int r = 0; r < 4; ++r) {
                int row = bm + wm + mt * 16 + ((lane >> 4) << 2) + r;
                float v = acc[mt][nt][r] + bv;
                if (is_root) out_root[(size_t)row * 256 + col] = f2bf(v);
                else         out_msg[(size_t)row * 1024 + (col - 256)] = f2bf(v);
            }
        }
    }
}

// ---------------------------------------------------------------------------
// Fused RGCN mid-layer: per 64-dst-row block, for r in {0..3, root}:
//   phase r<4 : gather h[src] for (dst,rel=r) edges, mean-scale -> LDS A-tile
//   phase r==4: copy own h rows -> LDS A-tile
//   then 8 MFMA K-steps vs W slice (k offset r*256 in packed Wl).
// Epilogue: +bias, ReLU, bf16 store h_out. h traffic is L3-resident (~65 MB).
// ---------------------------------------------------------------------------
__global__ __launch_bounds__(512) void rgcn_layer(
    const unsigned short* __restrict__ h,     // [M_PAD, 256]
    const unsigned short* __restrict__ Wl,    // [256 out][1280 k]
    const float* __restrict__ bias,           // [256]
    const int* __restrict__ rp4,              // [4*N_NODES + 1]
    const int* __restrict__ e_srcs,           // [E] srcs sorted by (dst, rel)
    const float* __restrict__ inv4,           // [N_NODES*4]
    unsigned short* __restrict__ h_out)       // [M_PAD, 256]
{
    __shared__ unsigned short mt[BM_L * LDM];   // 33792 B mean/self tile
    __shared__ unsigned short Bs[256 * 32];     // 16384 B weight K-step tile

    const int tid  = threadIdx.x;
    const int wave = tid >> 6, lane = tid & 63;
    const int bm = blockIdx.x * BM_L;

    // accumulate mapping: node = lane (64 nodes), col-slice = wave (32 cols)
    const int node  = bm + lane;
    const int cq    = wave * 32;                 // shorts
    const bool valid = node < N_NODES;

    // B staging: wave issues g = wave*2 + j; rows 16g..16g+15, swizzled chunks
    const int lr = lane >> 2;
    const int kg = ((lane & 3) ^ ((lr ^ (lr >> 2)) & 3)) * 8;

    // MFMA mapping
    const int fr  = lane & 15;
    const int q8  = (lane >> 4) * 8;
    const int qsw = (((lane >> 4) ^ fr ^ (fr >> 2)) & 3) * 8;
    const int wcol = wave * 32;

    float4 iv = valid ? *(const float4*)&inv4[(size_t)node * 4]
                      : make_float4(1.f, 1.f, 1.f, 1.f);

    f32x4 acc[4][2] = {};

    for (int r = 0; r < 5; ++r) {
        // ---- build A-tile slice in registers (no LDS touch yet) ----
        float4 am[8] = {};
        uint4 self[2];
        if (r < 4) {
            if (valid) {
                int lo = rp4[(size_t)node * 4 + r];
                int hi = rp4[(size_t)node * 4 + r + 1];
                for (int e = lo; e < hi; ++e) {
                    int s = e_srcs[e];
                    const uint4* hp = (const uint4*)(h + (size_t)s * 256 + cq);
                    #pragma unroll
                    for (int j = 0; j < 2; ++j) {
                        uint4 v = hp[j];
                        am[4*j+0].x += bflo(v.x); am[4*j+0].y += bfhi(v.x);
                        am[4*j+0].z += bflo(v.y); am[4*j+0].w += bfhi(v.y);
                        am[4*j+1].x += bflo(v.z); am[4*j+1].y += bfhi(v.z);
                        am[4*j+1].z += bflo(v.w); am[4*j+1].w += bfhi(v.w);
                    }
                    // second 16B half
                    #pragma unroll
                    for (int j = 0; j < 0; ++j) {}
                }
                // NOTE: loop above covers cols cq..cq+15 (2 uint4 = 16 bf16)?? no:
            }
        }
        // (restructured below — see full accumulate)
        // ---- actual accumulate: 32 cols = 4 x uint4 per edge ----
        if (r < 4) {
            am[0]=make_float4(0,0,0,0); am[1]=am[0]; am[2]=am[0]; am[3]=am[0];
            am[4]=am[0]; am[5]=am[0]; am[6]=am[0]; am[7]=am[0];
            if (valid) {
                int lo = rp4[(size_t)node * 4 + r];
                int hi = rp4[(size_t)node * 4 + r + 1];
                for (int e = lo; e < hi; ++e) {
                    int s = e_srcs[e];
                    const uint4* hp = (const uint4*)(h + (size_t)s * 256 + cq);
                    #pragma unroll
                    for (int j = 0; j < 4; ++j) {
                        uint2 v = ((const uint2*)hp)[j];
                        am[2*j+0].x += bflo(v.x); am[2*j+0].y += bfhi(v.x);
                        am[2*j+0].z += bflo(v.y); am[2*j+0].w += bfhi(v.y);
                        uint2 w = ((const uint2*)hp)[j]; (void)w;
                        am[2*j+1].x += 0.f;
                    }
                    // full 32 cols: 4 x uint4? replaced below
                }
            }
        }
        // ---- clean final accumulate implementation ----
        {
            #pragma unroll
            for (int j = 0; j < 8; ++j) am[j] = make_float4(0,0,0,0);
            if (r < 4) {
                if (valid) {
                    int lo = rp4[(size_t)node * 4 + r];
                    int hi = rp4[(size_t)node * 4 + r + 1];
                    for (int e = lo; e < hi; ++e) {
                        int s = e_srcs[e];
                        const uint4* hp = (const uint4*)(h + (size_t)s * 256 + cq);
                        uint4 v0 = hp[0];
                        uint4 v1 = hp[1];
                        am[0].x += bflo(v0.x); am[0].y += bfhi(v0.x);
                        am[0].z += bflo(v0.y); am[0].w += bfhi(v0.y);
                        am[1].x += bflo(v0.z); am[1].y += bfhi(v0.z);
                        am[1].z += bflo(v0.w); am[1].w += bfhi(v0.w);
                        am[2].x += bflo(v1.x); am[2].y += bfhi(v1.x);
                        am[2].z += bflo(v1.y); am[2].w += bfhi(v1.y);
                        am[3].x += bflo(v1.z); am[3].y += bfhi(v1.z);
                        am[3].z += bflo(v1.w); am[3].w += bfhi(v1.w);
                        const uint4* hp2 = hp + 2;
                        uint4 v2 = hp2[0];
                        uint4 v3 = hp2[1];
                        am[4].x += bflo(v2.x); am[4].y += bfhi(v2.x);
                        am[4].z += bflo(v2.y); am[4].w += bfhi(v2.y);
                        am[5].x += bflo(v2.z); am[5].y += bfhi(v2.z);
                        am[5].z += bflo(v2.w); am[5].w += bfhi(v2.w);
                        am[6].x += bflo(v3.x); am[6].y += bfhi(v3.x);
                        am[6].z += bflo(v3.y); am[6].w += bfhi(v3.y);
                        am[7].x += bflo(v3.z); am[7].y += bfhi(v3.z);
                        am[7].z += bflo(v3.w); am[7].w += bfhi(v3.w);
                    }
                }
            } else {
                // self rows (root term), scale 1
                const uint4* hp = (const uint4*)(h + (size_t)node * 256 + cq);
                self[0] = hp[0]; self[1] = hp[1];
                uint4 s2 = hp[2], s3 = hp[3];
                am[0].x = bflo(self[0].x); am[0].y = bfhi(self[0].x);
                am[0].z = bflo(self[0].y); am[0].w = bfhi(self[0].y);
                am[1].x = bflo(self[0].z); am[1].y = bfhi(self[0].z);
                am[1].z = bflo(self[0].w); am[1].w = bfhi(self[0].w);
                am[2].x = bflo(self[1].x); am[2].y = bfhi(self[1].x);
                am[2].z = bflo(self[1].y); am[2].w = bfhi(self[1].y);
                am[3].x = bflo(self[1].z); am[3].y = bfhi(self[1].z);
                am[3].z = bflo(self[1].w); am[3].w = bfhi(self[1].w);
                am[4].x = bflo(s2.x); am[4].y = bfhi(s2.x);
                am[4].z = bflo(s2.y); am[4].w = bfhi(s2.y);
                am[5].x = bflo(s2.z); am[5].y = bfhi(s2.z);
                am[5].z = bflo(s2.w); am[5].w = bfhi(s2.w);
                am[6].x = bflo(s3.x); am[6].y = bfhi(s3.x);
                am[6].z = bflo(s3.y); am[6].w = bfhi(s3.y);
                am[7].x = bflo(s3.z); am[7].y = bfhi(s3.z);
                am[7].z = bflo(s3.w); am[7].w = bfhi(s3.w);
            }
        }
        float sc = (r == 0) ? iv.x : (r == 1) ? iv.y : (r == 2) ? iv.z
                 : (r == 3) ? iv.w : 1.f;

        __syncthreads();   // previous phase's mt reads complete
        // write 32 cols (8B stores, 2-way banks = free)
        {
            unsigned short* dst = &mt[lane * LDM + cq];
            #pragma unroll
            for (int j = 0; j < 8; ++j) {
                ushort4 o;
                o.x = f2bf(am[j].x * sc); o.y = f2bf(am[j].y * sc);
                o.z = f2bf(am[j].z * sc); o.w = f2bf(am[j].w * sc);
                *(ushort4*)(dst + j * 4) = o;
            }
        }

        // ---- 8 MFMA K-steps against W slice (k offset r*256) ----
        const int rOff = r << 8;
        #pragma unroll 1
        for (int kk = 0; kk < 8; ++kk) {
            if (kk > 0) __syncthreads();      // Bs reads of prev step done
            {
                int g0 = wave * 2;
                gload16(Wl + (size_t)(g0 * 16 + lr) * N_TOT + rOff + kg + kk * 32,
                        Bs + g0 * 512);
                gload16(Wl + (size_t)((g0 + 1) * 16 + lr) * N_TOT + rOff + kg + kk * 32,
                        Bs + (g0 + 1) * 512);
            }
            __syncthreads();                  // staging + (kk==0: mt writes) visible

            short8 a[4], b[2];
            #pragma unroll
            for (int i = 0; i < 4; ++i)
                a[i] = *(const short8*)&mt[(i * 16 + fr) * LDM + kk * 32 + q8];
            #pragma unroll
            for (int nt = 0; nt < 2; ++nt)
                b[nt] = *(const short8*)&Bs[(wcol + nt * 16 + fr) * 32 + qsw];
            #pragma unroll
            for (int i = 0; i < 4; ++i)
                #pragma unroll
                for (int nt = 0; nt < 2; ++nt)
                    acc[i][nt] = __builtin_amdgcn_mfma_f32_16x16x32_bf16(
                        a[i], b[nt], acc[i][nt], 0, 0, 0);
        }
        __syncthreads();   // mt/Bs reads done before next phase rewrites
    }

    // ---- epilogue: +bias, ReLU, bf16 ----
    #pragma unroll
    for (int i = 0; i < 4; ++i) {
        #pragma unroll
        for (int nt = 0; nt < 2; ++nt) {
            int col = wcol + nt * 16 + fr;
            float bv = bias[col];
            #pragma unroll
            for (int rg = 0; rg < 4; ++rg) {
                int row = bm + i * 16 + ((lane >> 4) << 2) + rg;
                float v = fmaxf(acc[i][nt][rg] + bv, 0.f);
                h_out[(size_t)row * 256 + col] = f2bf(v);
            }
        }
    }
}

// ---------------------------------------------------------------------------
// Prep kernels
// ---------------------------------------------------------------------------
__global__ void convert_x(const float* __restrict__ x, unsigned short* __restrict__ xb) {
    size_t i = ((size_t)blockIdx.x * 256 + threadIdx.x) * 4;
    if (i >= (size_t)M_PAD * D_IN) return;
    ushort4 o;
    if (i < (size_t)N_NODES * D_IN) {
        float4 v = *(const float4*)&x[i];
        o.x = f2bf(v.x); o.y = f2bf(v.y); o.z = f2bf(v.z); o.w = f2bf(v.w);
    } else {
        o.x = o.y = o.z = o.w = 0;
    }
    *(ushort4*)&xb[i] = o;
}

__global__ void pack_w0(const float* __restrict__ root0, const float* __restrict__ w0,
                        unsigned short* __restrict__ Wt0) {
    int idx = blockIdx.x * 256 + threadIdx.x;            // Wt0[n][k], [1280 x 768]
    if (idx >= N_TOT * D_IN) return;
    int k = idx % D_IN, n = idx / D_IN;
    float v = (n < 256) ? root0[k * 256 + n]
                        : w0[(((n >> 8) - 1) * D_IN + k) * 256 + (n & 255)];
    Wt0[idx] = f2bf(v);
}

// WtR[l][n][k]: k<1024 -> w_rest[l][k>>8][k&255][n]; k>=1024 -> root_rest[l][k-1024][n]
__global__ void pack_wr(const float* __restrict__ root_rest, const float* __restrict__ w_rest,
                        unsigned short* __restrict__ WtR) {
    int idx = blockIdx.x * 256 + threadIdx.x;
    if (idx >= 5 * 256 * N_TOT) return;
    int k = idx % N_TOT; int t = idx / N_TOT; int n = t & 255; int l = t >> 8;
    float v = (k < 1024)
        ? w_rest[(((l * 4 + (k >> 8)) * 256) + (k & 255)) * 256 + n]
        : root_rest[(l * 256 + (k - 1024)) * 256 + n];
    WtR[idx] = f2bf(v);
}

__global__ void build_bias(const float* __restrict__ b0, float* __restrict__ eb) {
    int i = blockIdx.x * 256 + threadIdx.x;
    if (i < N_TOT) eb[i] = (i < 256) ? b0[i] : 0.f;
}

// ---------------------------------------------------------------------------
// (dst, rel)-sorted CSR over 4*N segments
// ---------------------------------------------------------------------------
__global__ void deg4_count(const int* __restrict__ dst, const int* __restrict__ rel,
                           int* __restrict__ deg4, int E) {
    int e = blockIdx.x * 256 + threadIdx.x;
    if (e < E) atomicAdd(&deg4[dst[e] * 4 + rel[e]], 1);
}

__global__ void invert4(const int* __restrict__ deg4, float* __restrict__ inv4, int n) {
    int i = blockIdx.x * 256 + threadIdx.x;
    if (i < n) inv4[i] = 1.0f / (float)max(deg4[i], 1);
}

__global__ __launch_bounds__(256) void block_sum(const int* __restrict__ deg,
                                                 int* __restrict__ bsum, int n) {
    __shared__ int s[256];
    int i = blockIdx.x * 256 + threadIdx.x;
    s[threadIdx.x] = (i < n) ? deg[i] : 0;
    __syncthreads();
    for (int o = 128; o > 0; o >>= 1) {
        if (threadIdx.x < o) s[threadIdx.x] += s[threadIdx.x + o];
        __syncthreads();
    }
    if (threadIdx.x == 0) bsum[blockIdx.x] = s[0];
}

__global__ __launch_bounds__(1024) void scan_bsum(const int* __restrict__ bsum,
                                                  int* __restrict__ boff, int nb) {
    __shared__ int s[1024];
    int t = threadIdx.x;
    int v0 = (t < nb) ? bsum[t] : 0;
    s[t] = v0;
    __syncthreads();
    for (int o = 1; o < 1024; o <<= 1) {
        int v = (t >= o) ? s[t - o] : 0;
        __syncthreads();
        s[t] += v;
        __syncthreads();
    }
    if (t < nb) boff[t] = s[t] - v0;   // exclusive
}

__global__ __launch_bounds__(256) void block_scan_write(
    const int* __restrict__ deg, const int* __restrict__ boff,
    int* __restrict__ row_ptr, int* __restrict__ cursor, int n, int total) {
    __shared__ int s[256];
    int t = threadIdx.x;
    int i = blockIdx.x * 256 + t;
    int v = (i < n) ? deg[i] : 0;
    s[t] = v;
    __syncthreads();
    for (int o = 1; o < 256; o <<= 1) {
        int u = (t >= o) ? s[t - o] : 0;
        __syncthreads();
        s[t] += u;
        __syncthreads();
    }
    int excl = s[t] - v + boff[blockIdx.x];
    if (i < n) { row_ptr[i] = excl; cursor[i] = excl; }
    if (blockIdx.x == 0 && t == 0) row_ptr[n] = total;
}

__global__ void place_edges4(const int* __restrict__ dst, const int* __restrict__ src,
                             const int* __restrict__ rel, int* __restrict__ cursor,
                             int* __restrict__ e_srcs, int E) {
    int e = blockIdx.x * 256 + threadIdx.x;
    if (e < E) {
        int p = atomicAdd(&cursor[dst[e] * 4 + rel[e]], 1);
        e_srcs[p] = src[e];
    }
}

// ---------------------------------------------------------------------------
// Layer-0 aggregate: h0 = relu(root[n] + sum_r inv_r * sum_e msg[src, r])
// ---------------------------------------------------------------------------
__global__ __launch_bounds__(256) void aggregate0(
    const unsigned short* __restrict__ rootb,   // [M_PAD,256]
    const unsigned short* __restrict__ msg,     // [M_PAD,1024]
    const int* __restrict__ rp4, const int* __restrict__ e_srcs,
    const float* __restrict__ inv4,
    unsigned short* __restrict__ h_out)         // [M_PAD,256]
{
    int node = blockIdx.x * 4 + (threadIdx.x >> 6);
    if (node >= N_NODES) return;
    int lane = threadIdx.x & 63;
    float4 iv = *(const float4*)&inv4[(size_t)node * 4];

    ushort4 rt = *(const ushort4*)&rootb[(size_t)node * 256 + lane * 4];
    float4 acc = make_float4(bf2f(rt.x), bf2f(rt.y), bf2f(rt.z), bf2f(rt.w));

    #pragma unroll
    for (int r = 0; r < 4; ++r) {
        int lo = rp4[(size_t)node * 4 + r], hi = rp4[(size_t)node * 4 + r + 1];
        float f = (r == 0) ? iv.x : (r == 1) ? iv.y : (r == 2) ? iv.z : iv.w;
        float4 s4 = make_float4(0, 0, 0, 0);
        for (int e = lo; e < hi; ++e) {
            int s = e_srcs[e];
            ushort4 m = *(const ushort4*)&msg[(size_t)s * 1024 + (r << 8) + lane * 4];
            s4.x += bf2f(m.x); s4.y += bf2f(m.y);
            s4.z += bf2f(m.z); s4.w += bf2f(m.w);
        }
        acc.x += s4.x * f; acc.y += s4.y * f;
        acc.z += s4.z * f; acc.w += s4.w * f;
    }
    ushort4 o;
    o.x = f2bf(fmaxf(acc.x, 0.f));
    o.y = f2bf(fmaxf(acc.y, 0.f));
    o.z = f2bf(fmaxf(acc.z, 0.f));
    o.w = f2bf(fmaxf(acc.w, 0.f));
    *(ushort4*)&h_out[(size_t)node * 256 + lane * 4] = o;
}

// ---------------------------------------------------------------------------
// Pooling + MLP head
// ---------------------------------------------------------------------------
__global__ __launch_bounds__(256) void pool_kernel(
    const unsigned short* __restrict__ h, const int* __restrict__ batch,
    float* __restrict__ g_feat)
{
    int g = blockIdx.x;
    int t = threadIdx.x;
    __shared__ int s_lo, s_hi;
    if (t == 0) {
        int lo = 0, hi = N_NODES;
        while (lo < hi) { int m = (lo + hi) >> 1; if (batch[m] < g) lo = m + 1; else hi = m; }
        s_lo = lo;
        int lo2 = lo, hi2 = N_NODES;
        while (lo2 < hi2) { int m = (lo2 + hi2) >> 1; if (batch[m] < g + 1) lo2 = m + 1; else hi2 = m; }
        s_hi = lo2;
    }
    __syncthreads();
    int lo = s_lo, hi = s_hi;
    float sum = 0.f, mx = 0.f;   // post-ReLU
    for (int n = lo; n < hi; ++n) {
        float v = bf2f(h[(size_t)n * 256 + t]);
        sum += v;
        mx = fmaxf(mx, v);
    }
    float cnt = (float)(hi - lo);
    g_feat[g * 512 + t]       = sum / fmaxf(cnt, 1.0f);
    g_feat[g * 512 + 256 + t] = (cnt > 0.f) ? mx : 0.f;
}

__global__ __launch_bounds__(128) void mlp_head(
    const float* __restrict__ g_feat,
    const float* __restrict__ fc1_w, const float* __restrict__ fc1_b,
    const float* __restrict__ fc2_w, const float* __restrict__ fc2_b,
    float* __restrict__ out)
{
    __shared__ float gf[512];
    __shared__ float partial[2];
    int g = blockIdx.x, t = threadIdx.x;
    for (int i = t; i < 512; i += 128) gf[i] = g_feat[g * 512 + i];
    __syncthreads();
    float acc = fc1_b[t];
    for (int i = 0; i < 512; ++i) acc += gf[i] * fc1_w[i * 128 + t];
    float h1 = fmaxf(acc, 0.f);
    float v = h1 * fc2_w[t];
    #pragma unroll
    for (int off = 32; off > 0; off >>= 1) v += __shfl_down(v, off);
    if ((t & 63) == 0) partial[t >> 6] = v;
    __syncthreads();
    if (t == 0) {
        float s = partial[0] + partial[1] + fc2_b[0];
        out[g] = 1.0f / (1.0f + expf(-s));
    }
}

// ---------------------------------------------------------------------------
// Launch
// ---------------------------------------------------------------------------
extern "C" void kernel_launch(void* const* d_in, const int* in_sizes, int n_in,
                              void* d_out, int out_size, void* d_ws, size_t ws_size,
                              hipStream_t stream) {
    const float* x          = (const float*)d_in[0];
    const int*   edge_index = (const int*)d_in[1];
    const int*   edge_attr  = (const int*)d_in[2];
    const int*   batch      = (const int*)d_in[3];
    const float* w0         = (const float*)d_in[4];
    const float* root0      = (const float*)d_in[5];
    const float* b0         = (const float*)d_in[6];
    const float* w_rest     = (const float*)d_in[7];
    const float* root_rest  = (const float*)d_in[8];
    const float* b_rest     = (const float*)d_in[9];
    const float* fc1_w      = (const float*)d_in[10];
    const float* fc1_b      = (const float*)d_in[11];
    const float* fc2_w      = (const float*)d_in[12];
    const float* fc2_b      = (const float*)d_in[13];
    float* out = (float*)d_out;

    const int* e_src = edge_index;
    const int* e_dst = edge_index + N_EDGES;

    char* p = (char*)d_ws;
    auto alloc = [&](size_t bytes) { char* q = p; p += (bytes + 255) & ~(size_t)255; return q; };
    unsigned short* x_bf   = (unsigned short*)alloc((size_t)M_PAD * D_IN * 2);   // 92 MB
    unsigned short* msgbuf = (unsigned short*)alloc((size_t)M_PAD * 1024 * 2);   // 123 MB
    unsigned short* hA     = (unsigned short*)alloc((size_t)M_PAD * 256 * 2);    // 31 MB
    unsigned short* hB     = (unsigned short*)alloc((size_t)M_PAD * 256 * 2);    // 31 MB
    unsigned short* Wt0    = (unsigned short*)alloc((size_t)N_TOT * D_IN * 2);
    unsigned short* WtR    = (unsigned short*)alloc((size_t)5 * 256 * N_TOT * 2);
    float*          ebias  = (float*)alloc(N_TOT * 4);
    float*          inv4   = (float*)alloc((size_t)N_NODES * 4 * 4);
    float*          g_feat = (float*)alloc((size_t)N_GRAPHS * 512 * 4);
    int*            deg4   = (int*)alloc((size_t)N_NODES * 4 * 4);
    int*            rp4    = (int*)alloc(((size_t)N_NODES * 4 + 1) * 4);
    int*            cursor4= (int*)alloc((size_t)N_NODES * 4 * 4);
    int*            bsum   = (int*)alloc(1024 * 4);
    int*            boff   = (int*)alloc(1024 * 4);
    int*            e_srcs = (int*)alloc((size_t)N_EDGES * 4);

    const int n4 = N_NODES * 4;                 // 240000
    const int nscan4 = cdiv(n4, 256);           // 938

    // --- prep ---
    hipMemsetAsync(deg4, 0, (size_t)n4 * 4, stream);
    convert_x<<<cdiv(M_PAD * D_IN / 4, 256), 256, 0, stream>>>(x, x_bf);
    pack_w0<<<cdiv(N_TOT * D_IN, 256), 256, 0, stream>>>(root0, w0, Wt0);
    pack_wr<<<cdiv(5 * 256 * N_TOT, 256), 256, 0, stream>>>(root_rest, w_rest, WtR);
    build_bias<<<cdiv(N_TOT, 256), 256, 0, stream>>>(b0, ebias);
    deg4_count<<<cdiv(N_EDGES, 256), 256, 0, stream>>>(e_dst, edge_attr, deg4, N_EDGES);
    invert4<<<cdiv(n4, 256), 256, 0, stream>>>(deg4, inv4, n4);
    block_sum<<<nscan4, 256, 0, stream>>>(deg4, bsum, n4);
    scan_bsum<<<1, 1024, 0, stream>>>(bsum, boff, nscan4);
    block_scan_write<<<nscan4, 256, 0, stream>>>(deg4, boff, rp4, cursor4, n4, N_EDGES);
    place_edges4<<<cdiv(N_EDGES, 256), 256, 0, stream>>>(e_dst, e_src, edge_attr,
                                                         cursor4, e_srcs, N_EDGES);

    // --- layer 0: transform-first GEMM (col blocks adjacent for A reuse) ---
    gemm_l0<<<dim3(N_TOT / 256, M_PAD / 128), 512, 0, stream>>>(
        x_bf, Wt0, ebias, hB, msgbuf, D_IN);
    aggregate0<<<cdiv(N_NODES, 4), 256, 0, stream>>>(hB, msgbuf, rp4, e_srcs, inv4, hA);

    // --- layers 1..5: fused gather+mean+GEMM ---
    unsigned short* cur = hA;
    unsigned short* nxt = hB;
    for (int L = 1; L < N_LAYERS; ++L) {
        rgcn_layer<<<M_PAD / BM_L, 512, 0, stream>>>(
            cur, WtR + (size_t)(L - 1) * 256 * N_TOT, b_rest + (size_t)(L - 1) * 256,
            rp4, e_srcs, inv4, nxt);
        unsigned short* t = cur; cur = nxt; nxt = t;
    }
    // final h in cur

    pool_kernel<<<N_GRAPHS, 256, 0, stream>>>(cur, batch, g_feat);
    mlp_head<<<N_GRAPHS, 128, 0, stream>>>(g_feat, fc1_w, fc1_b, fc2_w, fc2_b, out);
}